// Round 7
// baseline (113.085 us; speedup 1.0000x reference)
//
#include <hip/hip_runtime.h>
#include <math.h>

#define EPSF 1e-6f

typedef __attribute__((ext_vector_type(8))) short bf16x8;   // 8 bf16 = 4 VGPR (MFMA A/B frag)
typedef __attribute__((ext_vector_type(4))) float f32x4;    // MFMA C/D frag
typedef __attribute__((ext_vector_type(4))) unsigned short u16x4;
typedef __attribute__((ext_vector_type(8))) unsigned short u16x8;

constexpr int TT = 256, MT = 2000, NP = 7200;

static __device__ __forceinline__ unsigned short f2bf(float f) {
    unsigned int u = __float_as_uint(f);
    u += 0x7FFFu + ((u >> 16) & 1u);
    return (unsigned short)(u >> 16);
}
static __device__ __forceinline__ float frcp(float x) { return __builtin_amdgcn_rcpf(x); }

// Async global->LDS, 16B per lane. LDS dest is wave-uniform base (HW adds lane*16).
static __device__ __forceinline__ void gload_lds16(const unsigned short* g, unsigned short* l) {
    __builtin_amdgcn_global_load_lds(
        (const __attribute__((address_space(1))) unsigned int*)(g),
        (__attribute__((address_space(3))) unsigned int*)(l),
        16, 0, 0);
}

// ---------------- Kernel 1: fused prep (unchanged) ----------------
__global__ __launch_bounds__(256) void prep_kernel(const float* __restrict__ logits,
                                                   const float* __restrict__ lab,
                                                   unsigned short* __restrict__ probs,
                                                   unsigned short* __restrict__ nlab) {
    int b = blockIdx.x;
    if (b < 900) {
        int i = (b * 256 + threadIdx.x) * 8;
        float4 x0 = *reinterpret_cast<const float4*>(logits + i);
        float4 x1 = *reinterpret_cast<const float4*>(logits + i + 4);
        float v[8] = {x0.x, x0.y, x0.z, x0.w, x1.x, x1.y, x1.z, x1.w};
        u16x8 o;
#pragma unroll
        for (int j = 0; j < 8; ++j) {
            float s = frcp(1.0f + __expf(-v[j]));
            s = fminf(fmaxf(s, EPSF), 1.0f - EPSF);
            o[j] = f2bf(s);
        }
        *reinterpret_cast<u16x8*>(probs + i) = o;
    } else {
        int wave = threadIdx.x >> 6;
        int lane = threadIdx.x & 63;
        int m = (b - 900) * 4 + wave;               // [0,2000)
        float4 v = reinterpret_cast<const float4*>(lab)[m * (TT / 4) + lane];
        float s = v.x + v.y + v.z + v.w;
#pragma unroll
        for (int off = 32; off > 0; off >>= 1) s += __shfl_down(s, off);
        float inv = frcp(__shfl(s, 0) + EPSF);
        u16x4 o;
        o[0] = f2bf(v.x * inv); o[1] = f2bf(v.y * inv);
        o[2] = f2bf(v.z * inv); o[3] = f2bf(v.w * inv);
        *reinterpret_cast<u16x4*>(nlab + m * TT + lane * 4) = o;
    }
}

// ----- Kernel 2: PERSISTENT blocks, cross-tile pipeline (stage i+1 under epilogue i) -----
// R0-R6 ledger: every per-tile-block schedule (0-3 barriers, 2-5 blk/CU, private
// slices) sits at 35-46us -- the serial {stage -> mfma -> epilogue} path per tile
// is the limit, not sync or occupancy. The epilogue (~2000cy box-VALU + stores,
// register-only) is the natural slot to hide the NEXT tile's staging. Persistent
// 512-block grid (2/CU), each block loops ~7 tiles:
//   sync -> MFMA(i) -> sync -> issue stage(i+1)+boxprefetch(i+1) -> epilogue(i)
// Stage flight covered by epilogue; loop-top __syncthreads drains already-landed
// loads. Boxes double-buffered in regs (struct copy, const-indexed; rule #20).
// Full-K 64KB LDS, gl_lds + both-sides XOR swizzle (rule #21), XCD slab partition.
constexpr int NTX = 113, NTY = 32;                  // 3616 tiles, 64x64 each
constexpr int SLAB = 452;                           // tiles per XCD (3616/8)

struct BoxPre {                                     // 40 VGPR of prefetched boxes
    float4 tb0, tb1;                                // target boxes (per tj)
    float4 pb[8];                                   // pred boxes  [ti*4 + r]
};

__global__ __launch_bounds__(256, 2) void cost_mfma_kernel(
    const unsigned short* __restrict__ A,   // probs bf16 [NP][TT]
    const unsigned short* __restrict__ B,   // nlab  bf16 [MT][TT]
    const float* __restrict__ pbox,         // [NP][4] cxcywh
    const float* __restrict__ tbox,         // [MT][4] cxcywh
    float* __restrict__ out)                // [NP][MT] fp32
{
    __shared__ __align__(16) unsigned short As[64 * 256];   // 32 KB
    __shared__ __align__(16) unsigned short Bs[64 * 256];   // 32 KB

    const int x = blockIdx.x & 7;                   // XCD
    const int kb = blockIdx.x >> 3;                 // block-in-XCD [0,64)

    const int tid = threadIdx.x;
    const int lane = tid & 63, wave = tid >> 6;     // 4 waves
    const int wr = wave & 1, wc = wave >> 1;        // wave's 32x32 quadrant
    const int fr = lane & 15, quad = lane >> 4;     // fragment row / k-quad

    const int lro = lane >> 5;                      // staging: row within 1KB issue
    const int lch = lane & 31;                      // 16B chunk within 512B row

    const int xs = (fr & 7) << 4;                   // read-side swizzle
    const char* aB[2]; const char* bB[2];
#pragma unroll
    for (int t = 0; t < 2; ++t) {
        aB[t] = reinterpret_cast<const char*>(As) + (wr * 32 + t * 16 + fr) * 512;
        bB[t] = reinterpret_cast<const char*>(Bs) + (wc * 32 + t * 16 + fr) * 512;
    }

    auto stage = [&](int n0_, int m0_) {
#pragma unroll
        for (int i = 0; i < 8; ++i) {
            int row = wave * 16 + i * 2 + lro;
            int cs = (lch * 16) ^ ((row & 7) << 4);         // pre-swizzled source col
            int gn = n0_ + row; gn = gn > NP - 1 ? NP - 1 : gn;
            gload_lds16(A + gn * TT + (cs >> 1), &As[wave * 4096 + i * 512]);
        }
#pragma unroll
        for (int i = 0; i < 8; ++i) {
            int row = wave * 16 + i * 2 + lro;
            int cs = (lch * 16) ^ ((row & 7) << 4);
            int gm = m0_ + row; gm = gm > MT - 1 ? MT - 1 : gm;
            gload_lds16(B + gm * TT + (cs >> 1), &Bs[wave * 4096 + i * 512]);
        }
    };
    auto boxload = [&](int n0_, int m0_, BoxPre& bx) {
        {
            int gm = m0_ + wc * 32 + fr;            // tj = 0
            int g = gm < MT ? gm : MT - 1;
            bx.tb0 = *reinterpret_cast<const float4*>(&tbox[g * 4]);
        }
        {
            int gm = m0_ + wc * 32 + 16 + fr;       // tj = 1
            int g = gm < MT ? gm : MT - 1;
            bx.tb1 = *reinterpret_cast<const float4*>(&tbox[g * 4]);
        }
#pragma unroll
        for (int ti = 0; ti < 2; ++ti)
#pragma unroll
            for (int r = 0; r < 4; ++r) {
                int p = n0_ + wr * 32 + ti * 16 + quad * 4 + r;
                int g = p < NP ? p : NP - 1;
                bx.pb[ti * 4 + r] = *reinterpret_cast<const float4*>(&pbox[g * 4]);
            }
    };

    // ---- prologue: tile 0 in flight ----
    int joff = kb;
    int l = x * SLAB + joff;
    int n0 = (l >> 5) * 64, m0 = (l & 31) * 64;
    stage(n0, m0);
    BoxPre nxt; boxload(n0, m0, nxt);

    for (;;) {
        __syncthreads();                // vmcnt(0)+barrier: stage+boxes landed
        BoxPre cur = nxt;               // register copy, const-indexed
        const int cn0 = n0, cm0 = m0;

        // ---- MFMA(i): 32 MFMAs over K=256 from swizzled LDS ----
        f32x4 acc[2][2] = {};
        __builtin_amdgcn_s_setprio(1);
#pragma unroll
        for (int kk = 0; kk < 8; ++kk) {
            int cb = (kk * 64 + quad * 16) ^ xs;
            bf16x8 af[2], bg[2];
#pragma unroll
            for (int t = 0; t < 2; ++t) {
                af[t] = *reinterpret_cast<const bf16x8*>(aB[t] + cb);
                bg[t] = *reinterpret_cast<const bf16x8*>(bB[t] + cb);
            }
#pragma unroll
            for (int ti = 0; ti < 2; ++ti)
#pragma unroll
                for (int tj = 0; tj < 2; ++tj)
                    acc[ti][tj] = __builtin_amdgcn_mfma_f32_16x16x32_bf16(
                        af[ti], bg[tj], acc[ti][tj], 0, 0, 0);
        }
        __builtin_amdgcn_s_setprio(0);
        __syncthreads();                // all waves done reading LDS

        // ---- issue stage(i+1) + box prefetch(i+1); fly under epilogue(i) ----
        const bool more = (joff + 64) < SLAB;
        if (more) {
            joff += 64;
            l = x * SLAB + joff;
            n0 = (l >> 5) * 64; m0 = (l & 31) * 64;
            stage(n0, m0);
            boxload(n0, m0, nxt);
        }

        // ---- epilogue(i): box costs + stores from cur (registers only) ----
        float bcx[2], bcy[2], bww[2], bhh[2], bx1[2], by1[2], bx2[2], by2[2], areaB[2];
        int mj[2]; bool mv[2];
#pragma unroll
        for (int tj = 0; tj < 2; ++tj) {
            int gm = cm0 + wc * 32 + tj * 16 + fr;
            mv[tj] = gm < MT; mj[tj] = gm;
            float4 b = tj ? cur.tb1 : cur.tb0;
            bcx[tj] = b.x; bcy[tj] = b.y; bww[tj] = b.z; bhh[tj] = b.w;
            bx1[tj] = b.x - 0.5f * b.z; by1[tj] = b.y - 0.5f * b.w;
            bx2[tj] = b.x + 0.5f * b.z; by2[tj] = b.y + 0.5f * b.w;
            areaB[tj] = (bx2[tj] - bx1[tj]) * (by2[tj] - by1[tj]);
        }

#pragma unroll
        for (int ti = 0; ti < 2; ++ti) {
#pragma unroll
            for (int r = 0; r < 4; ++r) {
                int p = cn0 + wr * 32 + ti * 16 + quad * 4 + r;  // C/D: row = quad*4+reg
                if (p >= NP) continue;
                float4 pb4 = cur.pb[ti * 4 + r];
                float ax1 = pb4.x - 0.5f * pb4.z, ay1 = pb4.y - 0.5f * pb4.w;
                float ax2 = pb4.x + 0.5f * pb4.z, ay2 = pb4.y + 0.5f * pb4.w;
                float areaA = (ax2 - ax1) * (ay2 - ay1);
#pragma unroll
                for (int tj = 0; tj < 2; ++tj) {
                    if (!mv[tj]) continue;
                    float l1 = fabsf(pb4.x - bcx[tj]) + fabsf(pb4.y - bcy[tj]) +
                               fabsf(pb4.z - bww[tj]) + fabsf(pb4.w - bhh[tj]);
                    float ltx = fmaxf(ax1, bx1[tj]), lty = fmaxf(ay1, by1[tj]);
                    float rbx = fminf(ax2, bx2[tj]), rby = fminf(ay2, by2[tj]);
                    float iw = fmaxf(rbx - ltx, 0.0f), ih = fmaxf(rby - lty, 0.0f);
                    float inter = iw * ih;
                    float uni = areaA + areaB[tj] - inter;
                    float iou = inter * frcp(uni + EPSF);
                    float ex1 = fminf(ax1, bx1[tj]), ey1 = fminf(ay1, by1[tj]);
                    float ex2 = fmaxf(ax2, bx2[tj]), ey2 = fmaxf(ay2, by2[tj]);
                    float ew = fmaxf(ex2 - ex1, 0.0f), eh = fmaxf(ey2 - ey1, 0.0f);
                    float areaE = ew * eh;
                    float giou = iou - (areaE - uni) * frcp(areaE + EPSF);
                    float res = 5.0f * l1 - acc[ti][tj][r] - 2.0f * fmaxf(giou, -1.0f);
                    out[p * MT + mj[tj]] = res;
                }
            }
        }
        if (!more) break;
    }
}

extern "C" void kernel_launch(void* const* d_in, const int* in_sizes, int n_in,
                              void* d_out, int out_size, void* d_ws, size_t ws_size,
                              hipStream_t stream) {
    const float* pred_logits = (const float*)d_in[0];  // [8,900,256]
    const float* pred_boxes  = (const float*)d_in[1];  // [8,900,4]
    const float* tgt_boxes   = (const float*)d_in[2];  // [2000,4]
    const float* tgt_labels  = (const float*)d_in[3];  // [2000,256]
    float* out = (float*)d_out;                        // [7200,2000]

    unsigned short* probs = (unsigned short*)d_ws;     // 7200*256 bf16 (3.7 MB)
    unsigned short* nlab  = probs + NP * TT;           // 2000*256 bf16 (1.0 MB)

    prep_kernel<<<900 + 500, 256, 0, stream>>>(pred_logits, tgt_labels, probs, nlab);

    cost_mfma_kernel<<<512, 256, 0, stream>>>(probs, nlab, pred_boxes, tgt_boxes, out);
}

// Round 8
// 105.943 us; speedup vs baseline: 1.0674x; 1.0674x over previous
//
#include <hip/hip_runtime.h>
#include <math.h>

#define EPSF 1e-6f

typedef __attribute__((ext_vector_type(8))) short bf16x8;   // 8 bf16 = 4 VGPR (MFMA A/B frag)
typedef __attribute__((ext_vector_type(4))) float f32x4;    // MFMA C/D frag
typedef __attribute__((ext_vector_type(4))) unsigned short u16x4;
typedef __attribute__((ext_vector_type(8))) unsigned short u16x8;

constexpr int TT = 256, MT = 2000, NP = 7200;

static __device__ __forceinline__ unsigned short f2bf(float f) {
    unsigned int u = __float_as_uint(f);
    u += 0x7FFFu + ((u >> 16) & 1u);
    return (unsigned short)(u >> 16);
}
static __device__ __forceinline__ float frcp(float x) { return __builtin_amdgcn_rcpf(x); }

// ---------------- Kernel 1: fused prep (unchanged) ----------------
__global__ __launch_bounds__(256) void prep_kernel(const float* __restrict__ logits,
                                                   const float* __restrict__ lab,
                                                   unsigned short* __restrict__ probs,
                                                   unsigned short* __restrict__ nlab) {
    int b = blockIdx.x;
    if (b < 900) {
        int i = (b * 256 + threadIdx.x) * 8;
        float4 x0 = *reinterpret_cast<const float4*>(logits + i);
        float4 x1 = *reinterpret_cast<const float4*>(logits + i + 4);
        float v[8] = {x0.x, x0.y, x0.z, x0.w, x1.x, x1.y, x1.z, x1.w};
        u16x8 o;
#pragma unroll
        for (int j = 0; j < 8; ++j) {
            float s = frcp(1.0f + __expf(-v[j]));
            s = fminf(fmaxf(s, EPSF), 1.0f - EPSF);
            o[j] = f2bf(s);
        }
        *reinterpret_cast<u16x8*>(probs + i) = o;
    } else {
        int wave = threadIdx.x >> 6;
        int lane = threadIdx.x & 63;
        int m = (b - 900) * 4 + wave;               // [0,2000)
        float4 v = reinterpret_cast<const float4*>(lab)[m * (TT / 4) + lane];
        float s = v.x + v.y + v.z + v.w;
#pragma unroll
        for (int off = 32; off > 0; off >>= 1) s += __shfl_down(s, off);
        float inv = frcp(__shfl(s, 0) + EPSF);
        u16x4 o;
        o[0] = f2bf(v.x * inv); o[1] = f2bf(v.y * inv);
        o[2] = f2bf(v.z * inv); o[3] = f2bf(v.w * inv);
        *reinterpret_cast<u16x4*>(nlab + m * TT + lane * 4) = o;
    }
}

// ---------------- Kernel 2: R0 champion base + low-VALU epilogue ----------------
// R0-R7 ledger: seven schedule variants (0-3 barriers, 2-5 blk/CU, private
// slices, persistent pipeline) all land 35-46us; R0's reg-staged 3-barrier
// structure remains best (~35us). R2 PMC: VALUBusy 56% => ~25us of VALU issue
// -- the kernel is VALU-instruction-count bound. This round keeps R0's
// schedule byte-identical and cuts instructions:
//  * SWAPPED MFMA operands: acc=mfma(bg,af) => C/D row=m, col=p; the f32x4
//    acc holds 4 CONSECUTIVE m => epilogue stores are 4x dwordx4 instead of
//    16 scalar stores (-12 store issues, -~40 addr VALU).
//  * single-rcp GIoU (one transcendental/pair instead of two).
//  * areaA/areaB = w*h directly from cxcywh; res via 2 fma.
constexpr int NTX = 113, NTY = 32;                  // 3616 tiles
constexpr int LDR = 132;                            // LDS row stride (128 + 4 elems pad)

__global__ __launch_bounds__(256, 4) void cost_mfma_kernel(
    const unsigned short* __restrict__ A,   // probs bf16 [NP][TT]
    const unsigned short* __restrict__ B,   // nlab  bf16 [MT][TT]
    const float* __restrict__ pbox,         // [NP][4] cxcywh
    const float* __restrict__ tbox,         // [MT][4] cxcywh
    float* __restrict__ out)                // [NP][MT] fp32
{
    __shared__ __align__(16) unsigned short As[64 * LDR];   // 16.9 KB
    __shared__ __align__(16) unsigned short Bs[64 * LDR];   // 16.9 KB

    // XCD slab swizzle: XCD c gets contiguous l-range -> A-slab + all-B in its L2.
    int n = blockIdx.x;
    int l = (n & 7) * 452 + (n >> 3);
    const int n0 = (l >> 5) * 64;
    const int m0 = (l & 31) * 64;

    const int tid = threadIdx.x;
    const int lane = tid & 63, wave = tid >> 6;
    const int wr = wave & 1, wc = wave >> 1;        // wave's 32x32 quadrant
    const int fr = lane & 15, quad = lane >> 4;     // fragment row / k-quad

    const int s_row = tid >> 4;          // staging row base (+16 per i)
    const int s_ch  = tid & 15;          // 16 lanes cover one row's 256B

    // Clamped staging row indices (reused for both chunks).
    int gn4[4], gm4[4];
#pragma unroll
    for (int i = 0; i < 4; ++i) {
        int row = s_row + i * 16;
        int gn = n0 + row; gn4[i] = gn > NP - 1 ? NP - 1 : gn;
        int gm = m0 + row; gm4[i] = gm > MT - 1 ? MT - 1 : gm;
    }

    // Epilogue box prefetch (issued early, lands during staging).
    // SWAPPED layout: 8 target boxes (m = quad*4+r based), 2 pred boxes (fr based).
    float4 tbv[2][4]; int mrow[2];
#pragma unroll
    for (int tm = 0; tm < 2; ++tm) {
        mrow[tm] = m0 + wc * 32 + tm * 16 + quad * 4;
#pragma unroll
        for (int r = 0; r < 4; ++r) {
            int g = mrow[tm] + r; g = g < MT ? g : MT - 1;
            tbv[tm][r] = *reinterpret_cast<const float4*>(&tbox[g * 4]);
        }
    }
    float4 pbv[2]; int prow[2];
#pragma unroll
    for (int tp = 0; tp < 2; ++tp) {
        int p = n0 + wr * 32 + tp * 16 + fr;
        prow[tp] = p;
        int g = p < NP ? p : NP - 1;
        pbv[tp] = *reinterpret_cast<const float4*>(&pbox[g * 4]);
    }

    // ---- stage chunk 0 ----
    bf16x8 sa[4], sb[4];
#pragma unroll
    for (int i = 0; i < 4; ++i) {
        sa[i] = *reinterpret_cast<const bf16x8*>(&A[gn4[i] * TT + s_ch * 8]);
        sb[i] = *reinterpret_cast<const bf16x8*>(&B[gm4[i] * TT + s_ch * 8]);
    }
#pragma unroll
    for (int i = 0; i < 4; ++i) {
        int row = s_row + i * 16;
        *reinterpret_cast<bf16x8*>(&As[row * LDR + s_ch * 8]) = sa[i];
        *reinterpret_cast<bf16x8*>(&Bs[row * LDR + s_ch * 8]) = sb[i];
    }
    __syncthreads();

    // ---- issue chunk 1 global loads (fly during chunk-0 MFMA phase) ----
    bf16x8 sa1[4], sb1[4];
#pragma unroll
    for (int i = 0; i < 4; ++i) {
        sa1[i] = *reinterpret_cast<const bf16x8*>(&A[gn4[i] * TT + 128 + s_ch * 8]);
        sb1[i] = *reinterpret_cast<const bf16x8*>(&B[gm4[i] * TT + 128 + s_ch * 8]);
    }

    f32x4 acc[2][2] = {};                           // [tm][tp]
    // ---- MFMA on chunk 0 ----
#pragma unroll
    for (int kk = 0; kk < 4; ++kk) {
        bf16x8 af[2], bg[2];
#pragma unroll
        for (int t = 0; t < 2; ++t) {
            af[t] = *reinterpret_cast<const bf16x8*>(
                &As[(wr * 32 + t * 16 + fr) * LDR + kk * 32 + quad * 8]);
            bg[t] = *reinterpret_cast<const bf16x8*>(
                &Bs[(wc * 32 + t * 16 + fr) * LDR + kk * 32 + quad * 8]);
        }
#pragma unroll
        for (int tm = 0; tm < 2; ++tm)
#pragma unroll
            for (int tp = 0; tp < 2; ++tp)
                acc[tm][tp] = __builtin_amdgcn_mfma_f32_16x16x32_bf16(
                    bg[tm], af[tp], acc[tm][tp], 0, 0, 0);
    }
    __syncthreads();   // all waves done reading chunk 0

    // ---- write chunk 1 into LDS (loads have been in flight) ----
#pragma unroll
    for (int i = 0; i < 4; ++i) {
        int row = s_row + i * 16;
        *reinterpret_cast<bf16x8*>(&As[row * LDR + s_ch * 8]) = sa1[i];
        *reinterpret_cast<bf16x8*>(&Bs[row * LDR + s_ch * 8]) = sb1[i];
    }
    __syncthreads();

    // ---- MFMA on chunk 1 ----
#pragma unroll
    for (int kk = 0; kk < 4; ++kk) {
        bf16x8 af[2], bg[2];
#pragma unroll
        for (int t = 0; t < 2; ++t) {
            af[t] = *reinterpret_cast<const bf16x8*>(
                &As[(wr * 32 + t * 16 + fr) * LDR + kk * 32 + quad * 8]);
            bg[t] = *reinterpret_cast<const bf16x8*>(
                &Bs[(wc * 32 + t * 16 + fr) * LDR + kk * 32 + quad * 8]);
        }
#pragma unroll
        for (int tm = 0; tm < 2; ++tm)
#pragma unroll
            for (int tp = 0; tp < 2; ++tp)
                acc[tm][tp] = __builtin_amdgcn_mfma_f32_16x16x32_bf16(
                    bg[tm], af[tp], acc[tm][tp], 0, 0, 0);
    }

    // -------- epilogue: 2 pred x 8 target pairs, f32x4 vector stores --------
#pragma unroll
    for (int tp = 0; tp < 2; ++tp) {
        int p = prow[tp];
        if (p >= NP) continue;
        float4 pb = pbv[tp];
        float ax1 = pb.x - 0.5f * pb.z, ay1 = pb.y - 0.5f * pb.w;
        float ax2 = pb.x + 0.5f * pb.z, ay2 = pb.y + 0.5f * pb.w;
        float areaA = pb.z * pb.w;
        float* orow = out + (size_t)p * MT;
#pragma unroll
        for (int tm = 0; tm < 2; ++tm) {
            int mb = mrow[tm];
            if (mb >= MT) continue;                 // mb%4==0, MT%4==0 -> full vec ok
            f32x4 res;
#pragma unroll
            for (int r = 0; r < 4; ++r) {
                float4 b = tbv[tm][r];
                float bx1 = b.x - 0.5f * b.z, by1 = b.y - 0.5f * b.w;
                float bx2 = b.x + 0.5f * b.z, by2 = b.y + 0.5f * b.w;
                float areaB = b.z * b.w;
                float l1 = fabsf(pb.x - b.x) + fabsf(pb.y - b.y) +
                           fabsf(pb.z - b.z) + fabsf(pb.w - b.w);
                float ltx = fmaxf(ax1, bx1), lty = fmaxf(ay1, by1);
                float rbx = fminf(ax2, bx2), rby = fminf(ay2, by2);
                float iw = fmaxf(rbx - ltx, 0.0f), ih = fmaxf(rby - lty, 0.0f);
                float inter = iw * ih;
                float uni = areaA + areaB - inter;
                float ex1 = fminf(ax1, bx1), ey1 = fminf(ay1, by1);
                float ex2 = fmaxf(ax2, bx2), ey2 = fmaxf(ay2, by2);
                float areaE = (ex2 - ex1) * (ey2 - ey1);
                // single-rcp GIoU: inter/ue - (areaE-uni)/ae with common denom
                float ue = uni + EPSF, ae = areaE + EPSF;
                float g = (inter * ae - (areaE - uni) * ue) * frcp(ue * ae);
                res[r] = fmaf(-2.0f, fmaxf(g, -1.0f),
                              fmaf(5.0f, l1, -acc[tm][tp][r]));
            }
            *reinterpret_cast<f32x4*>(orow + mb) = res;
        }
    }
}

extern "C" void kernel_launch(void* const* d_in, const int* in_sizes, int n_in,
                              void* d_out, int out_size, void* d_ws, size_t ws_size,
                              hipStream_t stream) {
    const float* pred_logits = (const float*)d_in[0];  // [8,900,256]
    const float* pred_boxes  = (const float*)d_in[1];  // [8,900,4]
    const float* tgt_boxes   = (const float*)d_in[2];  // [2000,4]
    const float* tgt_labels  = (const float*)d_in[3];  // [2000,256]
    float* out = (float*)d_out;                        // [7200,2000]

    unsigned short* probs = (unsigned short*)d_ws;     // 7200*256 bf16 (3.7 MB)
    unsigned short* nlab  = probs + NP * TT;           // 2000*256 bf16 (1.0 MB)

    prep_kernel<<<900 + 500, 256, 0, stream>>>(pred_logits, tgt_labels, probs, nlab);

    cost_mfma_kernel<<<NTX * NTY, 256, 0, stream>>>(probs, nlab, pred_boxes, tgt_boxes, out);
}